// Round 17
// baseline (388.093 us; speedup 1.0000x reference)
//
#include <hip/hip_runtime.h>

// Problem constants
#define BB 256      // batch
#define CCH 512     // channels
#define HW 196      // 14*14 spatial
#define TT 197      // templates_b rows (196 + 1 negative)
#define TROWS 208   // padded T rows (13 * 16)
#define H1FRAG (7 * 7)            // half 1: mt 0..6
#define H2FRAG (6 * 7)            // half 2: mt 7..12
#define H1SHORTS (H1FRAG * 512)   // 25088 shorts = 50176 B
#define H2SHORTS (H2FRAG * 512)   // 21504 shorts = 43008 B

typedef __attribute__((ext_vector_type(8))) short bf16x8;
typedef __attribute__((ext_vector_type(4))) float f32x4;

__device__ __forceinline__ unsigned short f2bf(float f) {
    union { float f; unsigned u; } v; v.f = f;
    unsigned r = v.u + 0x7FFFu + ((v.u >> 16) & 1u);   // round-to-nearest-even
    return (unsigned short)(r >> 16);
}

// ---- prep: wgs 0..181 build the A-table in FRAGMENT-CONTIGUOUS order
// (mt-major): A[mt][kt][lane][j] = tb[mt*16+(lane&15)][kt*32+(lane>>4)*8+j]*tau.
// wg 182: gmax = max(templates_f) (center peak is inside every 14x14 window).
__global__ void prep(const float* __restrict__ tf, const float* __restrict__ tb,
                     float* __restrict__ wsf, unsigned short* __restrict__ tb_bf) {
    if (blockIdx.x < 182) {
        int i = blockIdx.x * 256 + threadIdx.x;     // 182*256 == 46592 exactly
        int frag = i >> 9;                          // 512 shorts per (mt,kt) block
        int s    = i & 511;
        int mt = frag / 7, kt = frag % 7;
        int lane = s >> 3, j = s & 7;
        int r = mt * 16 + (lane & 15);
        int k = kt * 32 + (lane >> 4) * 8 + j;
        const float tau = 0.5f / 196.0f;
        float v = (r < TT && k < HW) ? tb[r * HW + k] * tau : 0.0f;
        tb_bf[i] = f2bf(v);
    } else {
        __shared__ float red[256];
        float m = -1e30f;
        for (int i = threadIdx.x; i < HW * HW; i += 256) m = fmaxf(m, tf[i]);
        red[threadIdx.x] = m;
        __syncthreads();
        for (int s = 128; s > 0; s >>= 1) {
            if (threadIdx.x < s) red[threadIdx.x] = fmaxf(red[threadIdx.x], red[threadIdx.x + s]);
            __syncthreads();
        }
        if (threadIdx.x == 0) wsf[0] = red[0];
    }
}

// ---- fused kernel, LOW-REGISTER edition targeting 2 wgs/CU (8 waves/SIMD):
//  - stream: pass A argmax scan (transient regs), pass B re-read x (cache-hot)
//    + mask/stores + fr[7] pack (28 regs = only long-lived state)
//  - GEMM: mt-outer with ONE f32x4 acc; run TWICE (pass 1: colsums;
//    pass 2: recompute tr, fused px/S1 with part = S1 - px*ln(px))
//  - A-table half-staged (50KB buffer), restaged 4x from L2 (cheap)
// __launch_bounds__(1024, 8): 8 waves/EU -> <=64 unified regs -> 2 wgs/CU.
extern "C" __global__ __launch_bounds__(1024, 8)
void fused_one(const float* __restrict__ x, const float* __restrict__ tf,
               const float* __restrict__ pT, const unsigned short* __restrict__ tb_bf,
               const float* __restrict__ wsf,
               float* __restrict__ xm_out, float* __restrict__ mask_out,
               float* __restrict__ loss_out)
{
    extern __shared__ char smem[];
    unsigned short* Alds = (unsigned short*)smem;                 // [49][512] bf16 frags (half buffer)
    float* s_part = (float*)(smem + H1SHORTS * 2);                // [16][208]
    float* rAs    = s_part + 16 * TROWS;                          // [208] 1/A
    float* lAs    = rAs + TROWS;                                  // [208] ln A
    float* pTs    = lAs + TROWS;                                  // [208]
    float* red    = pTs + TROWS;                                  // [16]

    const int c    = blockIdx.x;
    const int tid  = threadIdx.x;
    const int lane = tid & 63;
    const int w    = tid >> 6;
    const int l15  = lane & 15, lg = lane >> 4;
    const float rg = 1.0f / wsf[0];

    // ---- stage A-table HALF 1 (mt 0..6)
    {
        const f32x4* src = (const f32x4*)tb_bf;
        f32x4* dst = (f32x4*)Alds;
        #pragma unroll
        for (int it = 0; it < 4; ++it) {
            int idx = tid + it * 1024;
            if (idx < H1SHORTS / 8) dst[idx] = src[idx];
        }
    }
    if (tid < TROWS) pTs[tid] = (tid < TT) ? pT[tid] : 0.0f;

    const int b = w * 16 + l15;
    const size_t rowoff = ((size_t)b * CCH + c) * HW;
    const float* xrow = x + rowoff;

    // ---- pass A: streaming argmax, minimal retention
    // j = kt*2+h -> k0 = (j>>1)*32 + lg*8 + (j&1)*4, ascending per lane
    float bv = -__builtin_inff(); int bi = 0;
    #pragma unroll
    for (int j = 0; j < 13; ++j) {
        const int k0 = (j < 12) ? ((j >> 1) * 32 + lg * 8 + (j & 1) * 4) : 192;
        if (j < 12 || lg == 0) {
            f32x4 xv = *(const f32x4*)(xrow + k0);
            #pragma unroll
            for (int e = 0; e < 4; ++e) {
                float v = xv[e];
                if (v > bv) { bv = v; bi = k0 + e; }
            }
        }
    }
    #pragma unroll
    for (int m = 16; m <= 32; m <<= 1) {   // reduce over lg (lanes l15+16g)
        float ov = __shfl_xor(bv, m, 64);
        int   oi = __shfl_xor(bi, m, 64);
        if (ov > bv || (ov == bv && oi < bi)) { bv = ov; bi = oi; }
    }

    // ---- pass B: re-read x (L2/L3-hot), sel, mask, stores, fr pack
    const float* selrow = tf + (size_t)bi * HW;
    float* xmrow = xm_out + rowoff;
    float* mkrow = mask_out + rowoff;
    bf16x8 fr[7];

    #pragma unroll
    for (int kt = 0; kt < 6; ++kt) {
        #pragma unroll
        for (int h = 0; h < 2; ++h) {
            const int k0 = kt * 32 + lg * 8 + h * 4;
            f32x4 sel = *(const f32x4*)(selrow + k0);
            f32x4 xv  = *(const f32x4*)(xrow + k0);
            f32x4 mk, xm;
            #pragma unroll
            for (int e = 0; e < 4; ++e) {
                float m = fmaxf(sel[e] * rg - 0.2f, 0.0f) * 5.0f;
                mk[e] = m;
                xm[e] = xv[e] * m;
            }
            *(f32x4*)(xmrow + k0) = xm;
            *(f32x4*)(mkrow + k0) = mk;
            #pragma unroll
            for (int e = 0; e < 4; ++e) fr[kt][h * 4 + e] = (short)f2bf(xm[e]);
        }
    }
    {   // kt=6: only lg==0 has real data (floats 192..195); rest zero-pad
        fr[6] = (bf16x8){0, 0, 0, 0, 0, 0, 0, 0};
        if (lg == 0) {
            f32x4 sel = *(const f32x4*)(selrow + 192);
            f32x4 xv  = *(const f32x4*)(xrow + 192);
            f32x4 mk, xm;
            #pragma unroll
            for (int e = 0; e < 4; ++e) {
                float m = fmaxf(sel[e] * rg - 0.2f, 0.0f) * 5.0f;
                mk[e] = m;
                xm[e] = xv[e] * m;
            }
            *(f32x4*)(xmrow + 192) = xm;
            *(f32x4*)(mkrow + 192) = mk;
            #pragma unroll
            for (int e = 0; e < 4; ++e) fr[6][e] = (short)f2bf(xm[e]);
        }
    }

    __syncthreads();   // B1: A half 1 staged

    const unsigned short* Abase = Alds + lane * 8;
    float* sp = s_part + w * TROWS;

    // ---- GEMM pass 1a (mt 0..6): colsums of exp(tr), one acc tile at a time
    #pragma unroll
    for (int mt = 0; mt < 7; ++mt) {
        f32x4 acc = (f32x4){0.f, 0.f, 0.f, 0.f};
        #pragma unroll
        for (int kt = 0; kt < 7; ++kt)
            acc = __builtin_amdgcn_mfma_f32_16x16x32_bf16(
                *(const bf16x8*)(Abase + (mt * 7 + kt) * 512), fr[kt], acc, 0, 0, 0);
        f32x4 s;
        #pragma unroll
        for (int e = 0; e < 4; ++e) s[e] = __expf(acc[e]);
        #pragma unroll
        for (int m = 1; m <= 8; m <<= 1) {
            #pragma unroll
            for (int e = 0; e < 4; ++e) s[e] += __shfl_xor(s[e], m, 64);
        }
        if (l15 == 0) *(f32x4*)(sp + mt * 16 + lg * 4) = s;
    }

    __syncthreads();   // B2: done reading half 1
    {   // restage HALF 2
        const f32x4* src = (const f32x4*)(tb_bf + H1SHORTS);
        f32x4* dst = (f32x4*)Alds;
        #pragma unroll
        for (int it = 0; it < 3; ++it) {
            int idx = tid + it * 1024;
            if (idx < H2SHORTS / 8) dst[idx] = src[idx];
        }
    }
    __syncthreads();   // B3: half 2 staged

    // ---- GEMM pass 1b (mt 7..12)
    #pragma unroll
    for (int mt = 7; mt < 13; ++mt) {
        f32x4 acc = (f32x4){0.f, 0.f, 0.f, 0.f};
        #pragma unroll
        for (int kt = 0; kt < 7; ++kt)
            acc = __builtin_amdgcn_mfma_f32_16x16x32_bf16(
                *(const bf16x8*)(Abase + ((mt - 7) * 7 + kt) * 512), fr[kt], acc, 0, 0, 0);
        f32x4 s;
        #pragma unroll
        for (int e = 0; e < 4; ++e) s[e] = __expf(acc[e]);
        #pragma unroll
        for (int m = 1; m <= 8; m <<= 1) {
            #pragma unroll
            for (int e = 0; e < 4; ++e) s[e] += __shfl_xor(s[e], m, 64);
        }
        if (l15 == 0) *(f32x4*)(sp + mt * 16 + lg * 4) = s;
    }

    __syncthreads();   // B4: s_part complete; done reading half 2

    // ---- rAs/lAs + restage HALF 1 (disjoint LDS regions, one barrier)
    if (tid < TROWS) {
        float s = 0.f;
        #pragma unroll
        for (int w2 = 0; w2 < 16; ++w2) s += s_part[w2 * TROWS + tid];
        rAs[tid] = 1.0f / s;
        lAs[tid] = __logf(s);
    }
    {
        const f32x4* src = (const f32x4*)tb_bf;
        f32x4* dst = (f32x4*)Alds;
        #pragma unroll
        for (int it = 0; it < 4; ++it) {
            int idx = tid + it * 1024;
            if (idx < H1SHORTS / 8) dst[idx] = src[idx];
        }
    }
    __syncthreads();   // B5

    // ---- GEMM pass 2a (mt 0..6): recompute tr, fuse px & S1
    float px = 0.f, S1 = 0.f;
    #pragma unroll
    for (int mt = 0; mt < 7; ++mt) {
        f32x4 acc = (f32x4){0.f, 0.f, 0.f, 0.f};
        #pragma unroll
        for (int kt = 0; kt < 7; ++kt)
            acc = __builtin_amdgcn_mfma_f32_16x16x32_bf16(
                *(const bf16x8*)(Abase + (mt * 7 + kt) * 512), fr[kt], acc, 0, 0, 0);
        const int t0 = mt * 16 + lg * 4;
        f32x4 ra = *(const f32x4*)(rAs + t0);
        f32x4 la = *(const f32x4*)(lAs + t0);
        f32x4 pt = *(const f32x4*)(pTs + t0);
        #pragma unroll
        for (int e = 0; e < 4; ++e) {
            float p = __expf(acc[e]) * ra[e];
            px += pt[e] * p;
            S1 += pt[e] * p * (acc[e] - la[e]);
        }
    }

    __syncthreads();   // B6: done reading half 1
    {   // restage HALF 2
        const f32x4* src = (const f32x4*)(tb_bf + H1SHORTS);
        f32x4* dst = (f32x4*)Alds;
        #pragma unroll
        for (int it = 0; it < 3; ++it) {
            int idx = tid + it * 1024;
            if (idx < H2SHORTS / 8) dst[idx] = src[idx];
        }
    }
    __syncthreads();   // B7

    // ---- GEMM pass 2b (mt 7..12)
    #pragma unroll
    for (int mt = 7; mt < 13; ++mt) {
        f32x4 acc = (f32x4){0.f, 0.f, 0.f, 0.f};
        #pragma unroll
        for (int kt = 0; kt < 7; ++kt)
            acc = __builtin_amdgcn_mfma_f32_16x16x32_bf16(
                *(const bf16x8*)(Abase + ((mt - 7) * 7 + kt) * 512), fr[kt], acc, 0, 0, 0);
        const int t0 = mt * 16 + lg * 4;
        f32x4 ra = *(const f32x4*)(rAs + t0);
        f32x4 la = *(const f32x4*)(lAs + t0);
        f32x4 pt = *(const f32x4*)(pTs + t0);
        #pragma unroll
        for (int e = 0; e < 4; ++e) {
            float p = __expf(acc[e]) * ra[e];
            px += pt[e] * p;
            S1 += pt[e] * p * (acc[e] - la[e]);
        }
    }

    // ---- finish: reduce over lg, part = S1 - px*ln(px), reduce over b
    px += __shfl_xor(px, 16, 64);
    px += __shfl_xor(px, 32, 64);
    S1 += __shfl_xor(S1, 16, 64);
    S1 += __shfl_xor(S1, 32, 64);
    float part = S1 - px * __logf(px);
    #pragma unroll
    for (int m = 1; m <= 8; m <<= 1) part += __shfl_xor(part, m, 64);
    if (lane == 0) red[w] = part;
    __syncthreads();
    if (tid == 0) {
        float s = 0.f;
        #pragma unroll
        for (int w2 = 0; w2 < 16; ++w2) s += red[w2];
        loss_out[c] = -s;
    }
}

extern "C" void kernel_launch(void* const* d_in, const int* in_sizes, int n_in,
                              void* d_out, int out_size, void* d_ws, size_t ws_size,
                              hipStream_t stream) {
    const float* x  = (const float*)d_in[0];
    const float* tf = (const float*)d_in[1];
    const float* tb = (const float*)d_in[2];
    const float* pT = (const float*)d_in[3];

    const size_t NOUT = (size_t)BB * CCH * HW;
    float* xm_out = (float*)d_out;
    float* mk_out = xm_out + NOUT;
    float* ls_out = mk_out + NOUT;

    float* wsf = (float*)d_ws;
    unsigned short* tb_bf = (unsigned short*)((char*)d_ws + 64);   // 93184 B

    prep<<<183, 256, 0, stream>>>(tf, tb, wsf, tb_bf);

    const size_t SMEM = (size_t)H1SHORTS * 2             // A half buffer: 50176
                      + 16 * TROWS * 4                   // s_part: 13312
                      + 3 * TROWS * 4 + 16 * 4;          // rAs + lAs + pTs + red = 66048
    (void)hipFuncSetAttribute((const void*)fused_one,
                              hipFuncAttributeMaxDynamicSharedMemorySize, (int)SMEM);
    fused_one<<<dim3(CCH), dim3(1024), SMEM, stream>>>(x, tf, pT, tb_bf, wsf,
                                                       xm_out, mk_out, ls_out);
}

// Round 18
// 168.077 us; speedup vs baseline: 2.3090x; 2.3090x over previous
//
#include <hip/hip_runtime.h>

// Problem constants
#define BB 256      // batch
#define CCH 512     // channels
#define HW 196      // 14*14 spatial
#define TT 197      // templates_b rows (196 + 1 negative)
#define TROWS 208   // padded T rows (13 * 16)
#define NFRAG (13 * 7)            // (mt,kt) fragment blocks
#define ASHORTS (NFRAG * 64 * 8)  // 46592 shorts = 93184 B
#define CST (CCH * TROWS)         // colp per-g stride
#define QMAX_SHORTS (4 * 7 * 512) // biggest quarter (4 mt) = 14336 shorts = 28672 B

typedef __attribute__((ext_vector_type(8))) short bf16x8;
typedef __attribute__((ext_vector_type(4))) float f32x4;
typedef __attribute__((ext_vector_type(4))) unsigned short us4;

__device__ __forceinline__ unsigned short f2bf(float f) {
    union { float f; unsigned u; } v; v.f = f;
    unsigned r = v.u + 0x7FFFu + ((v.u >> 16) & 1u);   // round-to-nearest-even
    return (unsigned short)(r >> 16);
}
__device__ __forceinline__ float bf2f(unsigned short h) {
    union { unsigned u; float f; } v; v.u = ((unsigned)h) << 16;
    return v.f;
}

// ---- prep: wgs 0..181 build the A-table in FRAGMENT-CONTIGUOUS order
// (mt-major): A[mt][kt][lane][j] = tb[mt*16+(lane&15)][kt*32+(lane>>4)*8+j]*tau.
// wg 182: gmax = max(templates_f) (center peak in every 14x14 window) + pT pad.
__global__ void prep(const float* __restrict__ tf, const float* __restrict__ tb,
                     const float* __restrict__ pT,
                     float* __restrict__ wsf, unsigned short* __restrict__ tb_bf,
                     float* __restrict__ pT_pad) {
    if (blockIdx.x < 182) {
        int i = blockIdx.x * 256 + threadIdx.x;     // 182*256 == 46592 exactly
        int frag = i >> 9;                          // 512 shorts per (mt,kt) block
        int s    = i & 511;
        int mt = frag / 7, kt = frag % 7;
        int lane = s >> 3, j = s & 7;
        int r = mt * 16 + (lane & 15);
        int k = kt * 32 + (lane >> 4) * 8 + j;
        const float tau = 0.5f / 196.0f;
        float v = (r < TT && k < HW) ? tb[r * HW + k] * tau : 0.0f;
        tb_bf[i] = f2bf(v);
    } else {
        if (threadIdx.x < TROWS)
            pT_pad[threadIdx.x] = (threadIdx.x < TT) ? pT[threadIdx.x] : 0.0f;
        __shared__ float red[256];
        float m = -1e30f;
        for (int i = threadIdx.x; i < HW * HW; i += 256) m = fmaxf(m, tf[i]);
        red[threadIdx.x] = m;
        __syncthreads();
        for (int s = 128; s > 0; s >>= 1) {
            if (threadIdx.x < s) red[threadIdx.x] = fmaxf(red[threadIdx.x], red[threadIdx.x + s]);
            __syncthreads();
        }
        if (threadIdx.x == 0) wsf[0] = red[0];
    }
}

// ---- K1: wg (c,g) = 64 batches of one channel, 4 waves, 256 threads.
// waves_per_eu(4,4) -> 128-reg budget: u[13] (dies into fr), fr[7], acc[13]
// (AGPR) all fit spill-free. A-table staged in QUARTERS (28KB LDS buffer) ->
// total LDS 32KB -> 4 wgs/CU co-resident, phases overlap ACROSS wgs.
// Outputs: xm/mask fp32, colp exp-colsum partial, tr tile bf16 (trs).
extern "C" __global__ __launch_bounds__(256)
__attribute__((amdgpu_waves_per_eu(4, 4)))
void k1_main(const float* __restrict__ x, const float* __restrict__ tf,
             const unsigned short* __restrict__ tb_bf, const float* __restrict__ wsf,
             float* __restrict__ xm_out, float* __restrict__ mask_out,
             float* __restrict__ colp, unsigned short* __restrict__ trs)
{
    __shared__ unsigned short Alds[QMAX_SHORTS];   // 28672 B quarter buffer
    __shared__ float s_col[4][TROWS];              // 3328 B

    const int tid  = threadIdx.x;
    const int lane = tid & 63;
    const int w    = tid >> 6;          // wave 0..3
    const int l15  = lane & 15, lg = lane >> 4;
    const int c    = blockIdx.x >> 2, g = blockIdx.x & 3;
    const float rg = 1.0f / wsf[0];

    // ---- stage quarter 0 (mt 0..3, 28 frags)
    {
        const f32x4* src = (const f32x4*)tb_bf;
        f32x4* dst = (f32x4*)Alds;
        #pragma unroll
        for (int it = 0; it < 7; ++it) dst[tid + it * 256] = src[tid + it * 256];
    }

    const int b = g * 64 + w * 16 + l15;
    const size_t rowoff = ((size_t)b * CCH + c) * HW;
    const float* xrow = x + rowoff;

    // ---- batched x loads (u dies into fr before GEMM)
    f32x4 u[13];
    #pragma unroll
    for (int kt = 0; kt < 6; ++kt) {
        u[2 * kt]     = *(const f32x4*)(xrow + kt * 32 + lg * 8);
        u[2 * kt + 1] = *(const f32x4*)(xrow + kt * 32 + lg * 8 + 4);
    }
    if (lg == 0) u[12] = *(const f32x4*)(xrow + 192);
    else         u[12] = (f32x4){-__builtin_inff(), -__builtin_inff(),
                                 -__builtin_inff(), -__builtin_inff()};

    // ---- argmax (k ascends within each lane's scan -> strict > keeps first)
    float bv = -__builtin_inff(); int bi = 0;
    #pragma unroll
    for (int j = 0; j < 13; ++j) {
        const int k0 = (j < 12) ? (((j >> 1) * 8 + lg * 2 + (j & 1)) * 4) : 192;
        #pragma unroll
        for (int e = 0; e < 4; ++e) {
            float v = u[j][e];
            if (v > bv) { bv = v; bi = k0 + e; }
        }
    }
    #pragma unroll
    for (int m = 16; m <= 32; m <<= 1) {   // reduce over lg
        float ov = __shfl_xor(bv, m, 64);
        int   oi = __shfl_xor(bi, m, 64);
        if (ov > bv || (ov == bv && oi < bi)) { bv = ov; bi = oi; }
    }

    // ---- mask, outputs, B-frag pack
    const float* selrow = tf + (size_t)bi * HW;
    float* xmrow = xm_out + rowoff;
    float* mkrow = mask_out + rowoff;
    bf16x8 fr[7];

    #pragma unroll
    for (int kt = 0; kt < 6; ++kt) {
        #pragma unroll
        for (int h = 0; h < 2; ++h) {
            const int k0 = kt * 32 + lg * 8 + h * 4;
            f32x4 sel = *(const f32x4*)(selrow + k0);
            f32x4 mk, xm;
            #pragma unroll
            for (int e = 0; e < 4; ++e) {
                float m = fmaxf(sel[e] * rg - 0.2f, 0.0f) * 5.0f;
                mk[e] = m;
                xm[e] = u[2 * kt + h][e] * m;
            }
            *(f32x4*)(xmrow + k0) = xm;
            *(f32x4*)(mkrow + k0) = mk;
            #pragma unroll
            for (int e = 0; e < 4; ++e) fr[kt][h * 4 + e] = (short)f2bf(xm[e]);
        }
    }
    {   // kt=6: only lg==0 has real data
        fr[6] = (bf16x8){0, 0, 0, 0, 0, 0, 0, 0};
        if (lg == 0) {
            f32x4 sel = *(const f32x4*)(selrow + 192);
            f32x4 mk, xm;
            #pragma unroll
            for (int e = 0; e < 4; ++e) {
                float m = fmaxf(sel[e] * rg - 0.2f, 0.0f) * 5.0f;
                mk[e] = m;
                xm[e] = u[12][e] * m;
            }
            *(f32x4*)(xmrow + 192) = xm;
            *(f32x4*)(mkrow + 192) = mk;
            #pragma unroll
            for (int e = 0; e < 4; ++e) fr[6][e] = (short)f2bf(xm[e]);
        }
    }

    // ---- GEMM over 4 A-table quarters: mt ranges {0-3, 4-6, 7-9, 10-12}
    f32x4 acc[13];
    #pragma unroll
    for (int mt = 0; mt < 13; ++mt) acc[mt] = (f32x4){0.f, 0.f, 0.f, 0.f};

    const unsigned short* Abase = Alds + lane * 8;

    __syncthreads();   // quarter 0 staged
    #pragma unroll
    for (int mt = 0; mt < 4; ++mt) {
        #pragma unroll
        for (int kt = 0; kt < 7; ++kt)
            acc[mt] = __builtin_amdgcn_mfma_f32_16x16x32_bf16(
                *(const bf16x8*)(Abase + (mt * 7 + kt) * 512), fr[kt], acc[mt], 0, 0, 0);
    }
    __syncthreads();   // done reading quarter 0

    #pragma unroll
    for (int q = 1; q < 4; ++q) {
        const int m0 = 4 + (q - 1) * 3;            // 4, 7, 10
        {   // stage quarter q (3 mt = 21 frags = 1344 f32x4)
            const f32x4* src = (const f32x4*)tb_bf + m0 * 7 * 64;
            f32x4* dst = (f32x4*)Alds;
            #pragma unroll
            for (int it = 0; it < 6; ++it) {
                int idx = tid + it * 256;
                if (idx < 1344) dst[idx] = src[idx];
            }
        }
        __syncthreads();   // quarter q staged
        #pragma unroll
        for (int mi = 0; mi < 3; ++mi) {
            const int mt = m0 + mi;
            #pragma unroll
            for (int kt = 0; kt < 7; ++kt)
                acc[mt] = __builtin_amdgcn_mfma_f32_16x16x32_bf16(
                    *(const bf16x8*)(Abase + (mi * 7 + kt) * 512), fr[kt], acc[mt], 0, 0, 0);
        }
        __syncthreads();   // done reading quarter q
    }

    // ---- trs store (bf16 tr tile) + exp colsums over this wave's 16 b
    unsigned short* trow = trs + (((size_t)c * 4 + g) * 64 + w * 16 + l15) * TROWS;
    #pragma unroll
    for (int mt = 0; mt < 13; ++mt) {
        us4 pk;
        #pragma unroll
        for (int e = 0; e < 4; ++e) pk[e] = f2bf(acc[mt][e]);
        *(us4*)(trow + mt * 16 + lg * 4) = pk;

        f32x4 s;
        #pragma unroll
        for (int e = 0; e < 4; ++e) s[e] = __expf(acc[mt][e]);
        #pragma unroll
        for (int m = 1; m <= 8; m <<= 1) {
            #pragma unroll
            for (int e = 0; e < 4; ++e) s[e] += __shfl_xor(s[e], m, 64);
        }
        if (l15 == 0) *(f32x4*)(&s_col[w][mt * 16 + lg * 4]) = s;
    }
    __syncthreads();
    if (tid < TROWS) {
        float s = s_col[0][tid] + s_col[1][tid] + s_col[2][tid] + s_col[3][tid];
        colp[(size_t)g * CST + c * TROWS + tid] = s;
    }
}

// ---- K2: loss from trs (bf16, L3-hot) + colp. wg (c,g), quad per b-row.
// part_b = S1 - px*ln(px), S1 = sum_t pT*p*(tr - lnA), p = exp(tr)/A.
extern "C" __global__ __launch_bounds__(256)
void k2_loss(const unsigned short* __restrict__ trs, const float* __restrict__ pT_pad,
             const float* __restrict__ colp, float* __restrict__ loss_part)
{
    __shared__ float rAs[TROWS];
    __shared__ float lAs[TROWS];
    __shared__ float pTs[TROWS];
    __shared__ float red[4];

    const int tid  = threadIdx.x;
    const int lane = tid & 63;
    const int w    = tid >> 6;
    const int c    = blockIdx.x >> 2, g = blockIdx.x & 3;

    if (tid < TROWS) {
        const float* cpc = colp + (size_t)c * TROWS + tid;
        float A = cpc[0] + cpc[CST] + cpc[2 * CST] + cpc[3 * CST];
        rAs[tid] = 1.0f / A;
        lAs[tid] = __logf(A);
        pTs[tid] = pT_pad[tid];
    }
    __syncthreads();

    const int p4 = tid & 3;
    const unsigned short* trow = trs + (((size_t)c * 4 + g) * 64 + (tid >> 2)) * TROWS;

    float px = 0.f, S1 = 0.f;
    #pragma unroll
    for (int j = 0; j < 13; ++j) {
        const int t0 = (p4 + 4 * j) * 4;
        us4 tv = *(const us4*)(trow + t0);
        #pragma unroll
        for (int e = 0; e < 4; ++e) {
            const int t = t0 + e;
            float tr = bf2f(tv[e]);
            float p  = __expf(tr) * rAs[t];
            px += pTs[t] * p;
            S1 += pTs[t] * p * (tr - lAs[t]);
        }
    }
    px += __shfl_xor(px, 1, 64);
    px += __shfl_xor(px, 2, 64);
    S1 += __shfl_xor(S1, 1, 64);
    S1 += __shfl_xor(S1, 2, 64);
    float part = (p4 == 0) ? (S1 - px * __logf(px)) : 0.0f;
    #pragma unroll
    for (int off = 4; off <= 32; off <<= 1) part += __shfl_xor(part, off, 64);
    if (lane == 0) red[w] = part;
    __syncthreads();
    if (tid == 0) loss_part[(size_t)c * 4 + g] = red[0] + red[1] + red[2] + red[3];
}

// ---- K3: fold 4 wg-partials per channel
__global__ void k3_fin(const float* __restrict__ lp, float* __restrict__ loss_out) {
    int c = blockIdx.x * 256 + threadIdx.x;
    if (c < CCH)
        loss_out[c] = -(lp[4 * c] + lp[4 * c + 1] + lp[4 * c + 2] + lp[4 * c + 3]);
}

// ================= fallback (ws too small): round-12 fused monolith =========
#define H1FRAG (7 * 7)
#define H2FRAG (6 * 7)
#define H1SHORTS (H1FRAG * 512)
#define H2SHORTS (H2FRAG * 512)

extern "C" __global__ __launch_bounds__(1024)
void fused_fb(const float* __restrict__ x, const float* __restrict__ tf,
              const float* __restrict__ pT, const unsigned short* __restrict__ tb_bf,
              const float* __restrict__ wsf,
              float* __restrict__ xm_out, float* __restrict__ mask_out,
              float* __restrict__ loss_out)
{
    extern __shared__ char smem[];
    unsigned short* Alds = (unsigned short*)smem;
    float* s_part = (float*)(smem + H1SHORTS * 2);
    float* rAs    = s_part + 16 * TROWS;
    float* pTs    = rAs + TROWS;
    float* red    = pTs + TROWS;

    const int c    = blockIdx.x;
    const int tid  = threadIdx.x;
    const int lane = tid & 63;
    const int w    = tid >> 6;
    const int l15  = lane & 15, lg = lane >> 4;
    const float rg = 1.0f / wsf[0];

    {
        const f32x4* src = (const f32x4*)tb_bf;
        f32x4* dst = (f32x4*)Alds;
        #pragma unroll
        for (int it = 0; it < 4; ++it) {
            int idx = tid + it * 1024;
            if (idx < H1SHORTS / 8) dst[idx] = src[idx];
        }
    }
    if (tid < TROWS) pTs[tid] = (tid < TT) ? pT[tid] : 0.0f;

    const int b = w * 16 + l15;
    const size_t rowoff = ((size_t)b * CCH + c) * HW;
    const float* xrow = x + rowoff;

    f32x4 u[13];
    #pragma unroll
    for (int kt = 0; kt < 6; ++kt) {
        u[2 * kt]     = *(const f32x4*)(xrow + kt * 32 + lg * 8);
        u[2 * kt + 1] = *(const f32x4*)(xrow + kt * 32 + lg * 8 + 4);
    }
    if (lg == 0) u[12] = *(const f32x4*)(xrow + 192);
    else         u[12] = (f32x4){-__builtin_inff(), -__builtin_inff(),
                                 -__builtin_inff(), -__builtin_inff()};

    float bv = -__builtin_inff(); int bi = 0;
    #pragma unroll
    for (int j = 0; j < 13; ++j) {
        const int k0 = (j < 12) ? (((j >> 1) * 8 + lg * 2 + (j & 1)) * 4) : 192;
        #pragma unroll
        for (int e = 0; e < 4; ++e) {
            float v = u[j][e];
            if (v > bv) { bv = v; bi = k0 + e; }
        }
    }
    #pragma unroll
    for (int m = 16; m <= 32; m <<= 1) {
        float ov = __shfl_xor(bv, m, 64);
        int   oi = __shfl_xor(bi, m, 64);
        if (ov > bv || (ov == bv && oi < bi)) { bv = ov; bi = oi; }
    }

    const float* selrow = tf + (size_t)bi * HW;
    float* xmrow = xm_out + rowoff;
    float* mkrow = mask_out + rowoff;
    bf16x8 fr[7];

    #pragma unroll
    for (int kt = 0; kt < 6; ++kt) {
        #pragma unroll
        for (int h = 0; h < 2; ++h) {
            const int k0 = kt * 32 + lg * 8 + h * 4;
            f32x4 sel = *(const f32x4*)(selrow + k0);
            f32x4 mk, xm;
            #pragma unroll
            for (int e = 0; e < 4; ++e) {
                float m = fmaxf(sel[e] * rg - 0.2f, 0.0f) * 5.0f;
                mk[e] = m;
                xm[e] = u[2 * kt + h][e] * m;
            }
            *(f32x4*)(xmrow + k0) = xm;
            *(f32x4*)(mkrow + k0) = mk;
            #pragma unroll
            for (int e = 0; e < 4; ++e) fr[kt][h * 4 + e] = (short)f2bf(xm[e]);
        }
    }
    {
        fr[6] = (bf16x8){0, 0, 0, 0, 0, 0, 0, 0};
        if (lg == 0) {
            f32x4 sel = *(const f32x4*)(selrow + 192);
            f32x4 mk, xm;
            #pragma unroll
            for (int e = 0; e < 4; ++e) {
                float m = fmaxf(sel[e] * rg - 0.2f, 0.0f) * 5.0f;
                mk[e] = m;
                xm[e] = u[12][e] * m;
            }
            *(f32x4*)(xmrow + 192) = xm;
            *(f32x4*)(mkrow + 192) = mk;
            #pragma unroll
            for (int e = 0; e < 4; ++e) fr[6][e] = (short)f2bf(xm[e]);
        }
    }

    __syncthreads();

    f32x4 acc[13];
    #pragma unroll
    for (int mt = 0; mt < 13; ++mt) acc[mt] = (f32x4){0.f, 0.f, 0.f, 0.f};

    const unsigned short* Abase = Alds + lane * 8;
    #pragma unroll
    for (int kt = 0; kt < 7; ++kt) {
        const bf16x8 bfrag = fr[kt];
        #pragma unroll
        for (int mt = 0; mt < 7; ++mt)
            acc[mt] = __builtin_amdgcn_mfma_f32_16x16x32_bf16(
                *(const bf16x8*)(Abase + (mt * 7 + kt) * 512), bfrag, acc[mt], 0, 0, 0);
    }
    __syncthreads();
    {
        const f32x4* src = (const f32x4*)(tb_bf + H1SHORTS);
        f32x4* dst = (f32x4*)Alds;
        #pragma unroll
        for (int it = 0; it < 3; ++it) {
            int idx = tid + it * 1024;
            if (idx < H2SHORTS / 8) dst[idx] = src[idx];
        }
    }
    __syncthreads();
    #pragma unroll
    for (int kt = 0; kt < 7; ++kt) {
        const bf16x8 bfrag = fr[kt];
        #pragma unroll
        for (int mt = 7; mt < 13; ++mt)
            acc[mt] = __builtin_amdgcn_mfma_f32_16x16x32_bf16(
                *(const bf16x8*)(Abase + ((mt - 7) * 7 + kt) * 512), bfrag, acc[mt], 0, 0, 0);
    }

    float* sp = s_part + w * TROWS;
    #pragma unroll
    for (int mt = 0; mt < 13; ++mt) {
        #pragma unroll
        for (int e = 0; e < 4; ++e) acc[mt][e] = __expf(acc[mt][e]);
        f32x4 s = acc[mt];
        #pragma unroll
        for (int m = 1; m <= 8; m <<= 1) {
            #pragma unroll
            for (int e = 0; e < 4; ++e) s[e] += __shfl_xor(s[e], m, 64);
        }
        if (l15 == 0) *(f32x4*)(sp + mt * 16 + lg * 4) = s;
    }
    __syncthreads();
    if (tid < TROWS) {
        float s = 0.f;
        #pragma unroll
        for (int w2 = 0; w2 < 16; ++w2) s += s_part[w2 * TROWS + tid];
        rAs[tid] = 1.0f / s;
    }
    __syncthreads();

    float px = 0.f;
    #pragma unroll
    for (int mt = 0; mt < 13; ++mt) {
        const int t0 = mt * 16 + lg * 4;
        f32x4 ra = *(const f32x4*)(rAs + t0);
        f32x4 pt = *(const f32x4*)(pTs + t0);
        #pragma unroll
        for (int e = 0; e < 4; ++e) {
            float p = acc[mt][e] * ra[e];
            acc[mt][e] = p;
            px += pt[e] * p;
        }
    }
    px += __shfl_xor(px, 16, 64);
    px += __shfl_xor(px, 32, 64);
    const float rpx = 1.0f / px;

    float part = 0.f;
    #pragma unroll
    for (int mt = 0; mt < 13; ++mt) {
        const int t0 = mt * 16 + lg * 4;
        f32x4 pt = *(const f32x4*)(pTs + t0);
        #pragma unroll
        for (int e = 0; e < 4; ++e) {
            float p = acc[mt][e];
            part += pt[e] * p * __logf(p * rpx);
        }
    }
    #pragma unroll
    for (int off = 32; off >= 1; off >>= 1) part += __shfl_xor(part, off, 64);
    if (lane == 0) red[w] = part;
    __syncthreads();
    if (tid == 0) {
        float s = 0.f;
        #pragma unroll
        for (int w2 = 0; w2 < 16; ++w2) s += red[w2];
        loss_out[c] = -s;
    }
}

extern "C" void kernel_launch(void* const* d_in, const int* in_sizes, int n_in,
                              void* d_out, int out_size, void* d_ws, size_t ws_size,
                              hipStream_t stream) {
    const float* x  = (const float*)d_in[0];
    const float* tf = (const float*)d_in[1];
    const float* tb = (const float*)d_in[2];
    const float* pT = (const float*)d_in[3];

    const size_t NOUT = (size_t)BB * CCH * HW;
    float* xm_out = (float*)d_out;
    float* mk_out = xm_out + NOUT;
    float* ls_out = mk_out + NOUT;

    // ws layout: wsf(64) | tb_bf @64 | pT_pad @93312 | colp @94208 | lpart | trs
    char* wsp = (char*)d_ws;
    float*          wsf    = (float*)wsp;
    unsigned short* tb_bf  = (unsigned short*)(wsp + 64);          // 93184 B
    float*          pT_pad = (float*)(wsp + 93312);                // 832 B
    float*          colp   = (float*)(wsp + 94208);                // 1703936 B
    float*          lpart  = (float*)(wsp + 1798144);              // 8192 B
    unsigned short* trs    = (unsigned short*)(wsp + 1806336);     // 54525952 B
    const bool big = ws_size >= (size_t)1806336 + 54525952;

    prep<<<183, 256, 0, stream>>>(tf, tb, pT, wsf, tb_bf, pT_pad);

    if (big) {
        k1_main<<<2048, 256, 0, stream>>>(x, tf, tb_bf, wsf, xm_out, mk_out, colp, trs);
        k2_loss<<<2048, 256, 0, stream>>>(trs, pT_pad, colp, lpart);
        k3_fin<<<2, 256, 0, stream>>>(lpart, ls_out);
    } else {
        const size_t SMEM = (size_t)H1SHORTS * 2 + 16 * TROWS * 4
                          + 2 * TROWS * 4 + 16 * 4;
        (void)hipFuncSetAttribute((const void*)fused_fb,
                                  hipFuncAttributeMaxDynamicSharedMemorySize, (int)SMEM);
        fused_fb<<<dim3(CCH), dim3(1024), SMEM, stream>>>(x, tf, pT, tb_bf, wsf,
                                                          xm_out, mk_out, ls_out);
    }
}

// Round 19
// 141.108 us; speedup vs baseline: 2.7503x; 1.1911x over previous
//
#include <hip/hip_runtime.h>

// Problem constants
#define BB 256      // batch
#define CCH 512     // channels
#define HW 196      // 14*14 spatial
#define TT 197      // templates_b rows (196 + 1 negative)
#define TROWS 208   // padded T rows (13 * 16)
#define NFRAG (13 * 7)            // (mt,kt) fragment blocks
#define ASHORTS (NFRAG * 64 * 8)  // 46592 shorts = 93184 B
#define RPW 64                    // rows per stream-wg
#define F4PW (RPW * 49)           // 3136 float4 per stream-wg

typedef __attribute__((ext_vector_type(8))) short bf16x8;
typedef __attribute__((ext_vector_type(4))) float f32x4;

__device__ __forceinline__ unsigned short f2bf(float f) {
    union { float f; unsigned u; } v; v.f = f;
    unsigned r = v.u + 0x7FFFu + ((v.u >> 16) & 1u);   // round-to-nearest-even
    return (unsigned short)(r >> 16);
}

// ---- prep: wgs 0..181 build the A-table in FRAGMENT-CONTIGUOUS order
// (mt-major): A[mt][kt][lane][j] = tb[mt*16+(lane&15)][kt*32+(lane>>4)*8+j]*tau.
// wg 182: gmax = max(templates_f) (center peak is inside every 14x14 window).
__global__ void prep(const float* __restrict__ tf, const float* __restrict__ tb,
                     float* __restrict__ wsf, unsigned short* __restrict__ tb_bf) {
    if (blockIdx.x < 182) {
        int i = blockIdx.x * 256 + threadIdx.x;     // 182*256 == 46592 exactly
        int frag = i >> 9;                          // 512 shorts per (mt,kt) block
        int s    = i & 511;
        int mt = frag / 7, kt = frag % 7;
        int lane = s >> 3, j = s & 7;
        int r = mt * 16 + (lane & 15);
        int k = kt * 32 + (lane >> 4) * 8 + j;
        const float tau = 0.5f / 196.0f;
        float v = (r < TT && k < HW) ? tb[r * HW + k] * tau : 0.0f;
        tb_bf[i] = f2bf(v);
    } else {
        __shared__ float red[256];
        float m = -1e30f;
        for (int i = threadIdx.x; i < HW * HW; i += 256) m = fmaxf(m, tf[i]);
        red[threadIdx.x] = m;
        __syncthreads();
        for (int s = 128; s > 0; s >>= 1) {
            if (threadIdx.x < s) red[threadIdx.x] = fmaxf(red[threadIdx.x], red[threadIdx.x + s]);
            __syncthreads();
        }
        if (threadIdx.x == 0) wsf[0] = red[0];
    }
}

// ---- k_stream3: WAVE-CONTIGUOUS streamer. wg = 64 consecutive (b,c) rows
// (12544 floats contiguous). Pass 1: 13 wave-contiguous float4 loads/thread,
// kept in u[] AND mirrored to LDS. Argmax per row from LDS (quad per row,
// first-index tie rule). Pass 2: per linear idx, row = idx/49, sel from
// L2-hot tf, mask math, wave-contiguous xm/mask stores. Every HBM stream
// (x read, xm write, mask write) is lane-contiguous: 1KB/wave-instruction.
extern "C" __global__ __launch_bounds__(256, 4)
void k_stream3(const float* __restrict__ x, const float* __restrict__ tf,
               const float* __restrict__ wsf,
               float* __restrict__ xm_out, float* __restrict__ mask_out)
{
    __shared__ float xs[RPW * HW];   // 50176 B
    __shared__ int   biL[RPW];

    const int tid = threadIdx.x;
    const float rg = 1.0f / wsf[0];
    const size_t base4 = (size_t)blockIdx.x * F4PW;   // in float4 units
    const f32x4* x4 = (const f32x4*)x + base4;
    f32x4* xs4 = (f32x4*)xs;

    // ---- pass 1: wave-contiguous loads (batched), mirror to LDS
    f32x4 u[13];
    #pragma unroll
    for (int k = 0; k < 12; ++k) u[k] = x4[tid + k * 256];
    if (tid < 64) u[12] = x4[tid + 3072];
    #pragma unroll
    for (int k = 0; k < 12; ++k) xs4[tid + k * 256] = u[k];
    if (tid < 64) xs4[tid + 3072] = u[12];
    __syncthreads();

    // ---- argmax per row (quad per row, LDS-sourced)
    {
        const int row = tid >> 2;           // 0..63
        const int q   = tid & 3;
        const int nch = (q == 0) ? 13 : 12; // q=0 also takes chunk 48
        float bv = -__builtin_inff(); int bi = 0;
        #pragma unroll
        for (int j = 0; j < 13; ++j) if (j < nch) {
            const int ch = q + 4 * j;       // float4 index within row
            f32x4 xv = xs4[row * 49 + ch];
            const int k0 = ch * 4;
            #pragma unroll
            for (int e = 0; e < 4; ++e) {
                float v = xv[e];
                if (v > bv) { bv = v; bi = k0 + e; }   // k ascends per lane
            }
        }
        #pragma unroll
        for (int m = 1; m <= 2; m <<= 1) {
            float ov = __shfl_xor(bv, m, 64);
            int   oi = __shfl_xor(bi, m, 64);
            if (ov > bv || (ov == bv && oi < bi)) { bv = ov; bi = oi; }
        }
        if (q == 0) biL[row] = bi;
    }
    __syncthreads();

    // ---- pass 2: mask + wave-contiguous stores (x from retained u[])
    const f32x4* tf4 = (const f32x4*)tf;
    f32x4* xm4 = (f32x4*)xm_out + base4;
    f32x4* mk4 = (f32x4*)mask_out + base4;

    #pragma unroll
    for (int k = 0; k < 13; ++k) {
        const int idx = tid + k * 256;
        if (k < 12 || idx < F4PW) {
            const int rl = idx / 49;        // magic-mul const div
            const int j  = idx - rl * 49;
            const int bi = biL[rl];
            f32x4 sel = tf4[bi * 49 + j];
            f32x4 xv  = u[k];
            f32x4 mk, xm;
            #pragma unroll
            for (int e = 0; e < 4; ++e) {
                float m = fmaxf(sel[e] * rg - 0.2f, 0.0f) * 5.0f;
                mk[e] = m;
                xm[e] = xv[e] * m;
            }
            xm4[idx] = xm;
            mk4[idx] = mk;
        }
    }
}

// ---- k_gemm_loss: round-11 verbatim (known-good). Per-channel GEMM +
// softmax + MI loss. One wg (1024 thr, 16 waves) per channel. B-frags packed
// from xm fp32 (L3-hot). A-table staged to LDS fragment-contiguous ->
// conflict-free sequential ds_read_b128.
extern "C" __global__ __launch_bounds__(1024)
void k_gemm_loss(const float* __restrict__ xm, const float* __restrict__ pT,
                 const unsigned short* __restrict__ tb_bf,
                 float* __restrict__ loss_out)
{
    extern __shared__ char smem[];
    unsigned short* Alds = (unsigned short*)smem;                 // [91][512] bf16 frags
    float* s_part = (float*)(smem + ASHORTS * 2);                 // [16][208]
    float* rAs    = s_part + 16 * TROWS;                          // [208]
    float* pTs    = rAs + TROWS;                                  // [208]
    float* red    = pTs + TROWS;                                  // [16]

    const int c    = blockIdx.x;
    const int tid  = threadIdx.x;
    const int lane = tid & 63;
    const int w    = tid >> 6;
    const int l15  = lane & 15, lg = lane >> 4;

    // ---- stage A-table into LDS (5824 x 16B chunks over 1024 threads)
    {
        const f32x4* src = (const f32x4*)tb_bf;
        f32x4* dst = (f32x4*)Alds;
        #pragma unroll
        for (int it = 0; it < 6; ++it) {
            int idx = tid + it * 1024;
            if (idx < ASHORTS / 8) dst[idx] = src[idx];
        }
    }
    if (tid < TROWS) pTs[tid] = (tid < TT) ? pT[tid] : 0.0f;

    const int b = w * 16 + l15;
    const float* xrow = xm + ((size_t)b * CCH + c) * HW;

    // ---- B-frag pack straight from xm
    bf16x8 fr[7];
    #pragma unroll
    for (int kt = 0; kt < 6; ++kt) {
        f32x4 u0 = *(const f32x4*)(xrow + kt * 32 + lg * 8);
        f32x4 u1 = *(const f32x4*)(xrow + kt * 32 + lg * 8 + 4);
        #pragma unroll
        for (int e = 0; e < 4; ++e) {
            fr[kt][e]     = (short)f2bf(u0[e]);
            fr[kt][e + 4] = (short)f2bf(u1[e]);
        }
    }
    fr[6] = (bf16x8){0, 0, 0, 0, 0, 0, 0, 0};
    if (lg == 0) {
        f32x4 u0 = *(const f32x4*)(xrow + 192);
        #pragma unroll
        for (int e = 0; e < 4; ++e) fr[6][e] = (short)f2bf(u0[e]);
    }

    __syncthreads();   // A-table staged -> visible to all waves

    // ---- GEMM: tr[t = mt*16+lg*4+e][b = w*16+l15]; A-frags contiguous
    // 1024B LDS blocks: addr = (mt*7+kt)*1024B + lane*16B (seq, 0-conflict)
    f32x4 acc[13];
    #pragma unroll
    for (int mt = 0; mt < 13; ++mt) acc[mt] = (f32x4){0.f, 0.f, 0.f, 0.f};

    const unsigned short* Abase = Alds + lane * 8;
    #pragma unroll
    for (int kt = 0; kt < 7; ++kt) {
        const bf16x8 bfrag = fr[kt];
        #pragma unroll
        for (int mt = 0; mt < 13; ++mt) {
            bf16x8 afrag = *(const bf16x8*)(Abase + (mt * 7 + kt) * 512);
            acc[mt] = __builtin_amdgcn_mfma_f32_16x16x32_bf16(afrag, bfrag, acc[mt], 0, 0, 0);
        }
    }

    // ---- Phase A: exp in-register, col-sum over this wave's 16 b, cross-wave via LDS
    float* sp = s_part + w * TROWS;
    #pragma unroll
    for (int mt = 0; mt < 13; ++mt) {
        #pragma unroll
        for (int e = 0; e < 4; ++e) acc[mt][e] = __expf(acc[mt][e]);
        f32x4 s = acc[mt];
        #pragma unroll
        for (int m = 1; m <= 8; m <<= 1) {
            #pragma unroll
            for (int e = 0; e < 4; ++e) s[e] += __shfl_xor(s[e], m, 64);
        }
        if (l15 == 0) *(f32x4*)(sp + mt * 16 + lg * 4) = s;
    }
    __syncthreads();
    if (tid < TROWS) {
        float s = 0.f;
        #pragma unroll
        for (int w2 = 0; w2 < 16; ++w2) s += s_part[w2 * TROWS + tid];
        rAs[tid] = 1.0f / s;
    }
    __syncthreads();

    // ---- Phase B: p = exp*rA, px[b] = sum_t pT*p
    float px = 0.f;
    #pragma unroll
    for (int mt = 0; mt < 13; ++mt) {
        const int t0 = mt * 16 + lg * 4;
        f32x4 ra = *(const f32x4*)(rAs + t0);
        f32x4 pt = *(const f32x4*)(pTs + t0);
        #pragma unroll
        for (int e = 0; e < 4; ++e) {
            float p = acc[mt][e] * ra[e];
            acc[mt][e] = p;
            px += pt[e] * p;
        }
    }
    px += __shfl_xor(px, 16, 64);
    px += __shfl_xor(px, 32, 64);
    const float rpx = 1.0f / px;

    // ---- Phase C: loss partial = sum_t pT * p * log(p/px)
    float part = 0.f;
    #pragma unroll
    for (int mt = 0; mt < 13; ++mt) {
        const int t0 = mt * 16 + lg * 4;
        f32x4 pt = *(const f32x4*)(pTs + t0);
        #pragma unroll
        for (int e = 0; e < 4; ++e) {
            float p = acc[mt][e];
            part += pt[e] * p * __logf(p * rpx);
        }
    }
    #pragma unroll
    for (int off = 32; off >= 1; off >>= 1) part += __shfl_xor(part, off, 64);
    if (lane == 0) red[w] = part;
    __syncthreads();
    if (tid == 0) {
        float s = 0.f;
        #pragma unroll
        for (int w2 = 0; w2 < 16; ++w2) s += red[w2];
        loss_out[c] = -s;
    }
}

extern "C" void kernel_launch(void* const* d_in, const int* in_sizes, int n_in,
                              void* d_out, int out_size, void* d_ws, size_t ws_size,
                              hipStream_t stream) {
    const float* x  = (const float*)d_in[0];
    const float* tf = (const float*)d_in[1];
    const float* tb = (const float*)d_in[2];
    const float* pT = (const float*)d_in[3];

    const size_t NOUT = (size_t)BB * CCH * HW;
    float* xm_out = (float*)d_out;
    float* mk_out = xm_out + NOUT;
    float* ls_out = mk_out + NOUT;

    float* wsf = (float*)d_ws;
    unsigned short* tb_bf = (unsigned short*)((char*)d_ws + 64);   // 93184 B

    prep<<<183, 256, 0, stream>>>(tf, tb, wsf, tb_bf);
    k_stream3<<<(BB * CCH) / RPW, 256, 0, stream>>>(x, tf, wsf, xm_out, mk_out);

    const size_t SMEM = (size_t)ASHORTS * 2 + 16 * TROWS * 4
                      + TROWS * 4 + TROWS * 4 + 16 * 4;     // 108224 B
    (void)hipFuncSetAttribute((const void*)k_gemm_loss,
                              hipFuncAttributeMaxDynamicSharedMemorySize, (int)SMEM);
    k_gemm_loss<<<dim3(CCH), dim3(1024), SMEM, stream>>>(xm_out, pT, tb_bf, ls_out);
}

// Round 20
// 140.546 us; speedup vs baseline: 2.7613x; 1.0040x over previous
//
#include <hip/hip_runtime.h>

// Problem constants
#define BB 256      // batch
#define CCH 512     // channels
#define HW 196      // 14*14 spatial
#define TT 197      // templates_b rows (196 + 1 negative)
#define TROWS 208   // padded T rows (13 * 16)
#define NFRAG (13 * 7)            // (mt,kt) fragment blocks
#define ASHORTS (NFRAG * 64 * 8)  // 46592 shorts = 93184 B
#define RPW 32                    // rows per stream-wg (25KB LDS -> 6 wgs/CU)
#define F4PW (RPW * 49)           // 1568 float4 per stream-wg

typedef __attribute__((ext_vector_type(8))) short bf16x8;
typedef __attribute__((ext_vector_type(4))) float f32x4;

__device__ __forceinline__ unsigned short f2bf(float f) {
    union { float f; unsigned u; } v; v.f = f;
    unsigned r = v.u + 0x7FFFu + ((v.u >> 16) & 1u);   // round-to-nearest-even
    return (unsigned short)(r >> 16);
}

// ---- prep: wgs 0..181 build the A-table in FRAGMENT-CONTIGUOUS order
// (mt-major): A[mt][kt][lane][j] = tb[mt*16+(lane&15)][kt*32+(lane>>4)*8+j]*tau.
// wg 182: gmax = max(templates_f) (center peak is inside every 14x14 window).
__global__ void prep(const float* __restrict__ tf, const float* __restrict__ tb,
                     float* __restrict__ wsf, unsigned short* __restrict__ tb_bf) {
    if (blockIdx.x < 182) {
        int i = blockIdx.x * 256 + threadIdx.x;     // 182*256 == 46592 exactly
        int frag = i >> 9;                          // 512 shorts per (mt,kt) block
        int s    = i & 511;
        int mt = frag / 7, kt = frag % 7;
        int lane = s >> 3, j = s & 7;
        int r = mt * 16 + (lane & 15);
        int k = kt * 32 + (lane >> 4) * 8 + j;
        const float tau = 0.5f / 196.0f;
        float v = (r < TT && k < HW) ? tb[r * HW + k] * tau : 0.0f;
        tb_bf[i] = f2bf(v);
    } else {
        __shared__ float red[256];
        float m = -1e30f;
        for (int i = threadIdx.x; i < HW * HW; i += 256) m = fmaxf(m, tf[i]);
        red[threadIdx.x] = m;
        __syncthreads();
        for (int s = 128; s > 0; s >>= 1) {
            if (threadIdx.x < s) red[threadIdx.x] = fmaxf(red[threadIdx.x], red[threadIdx.x + s]);
            __syncthreads();
        }
        if (threadIdx.x == 0) wsf[0] = red[0];
    }
}

// ---- k_stream3: WAVE-CONTIGUOUS streamer, small-tile edition. wg = 32
// consecutive (b,c) rows (6272 floats contiguous). LDS 25KB -> 6 wgs/CU
// (24 waves/CU TLP). Pass 1: 7 wave-contiguous float4 loads/thread, kept in
// u[] AND mirrored to LDS. Argmax per row from LDS (8 threads/row,
// first-index tie rule). Pass 2: per linear idx, row = idx/49, sel from
// L2-hot tf, mask math, wave-contiguous xm/mask stores. Every HBM stream
// (x read, xm write, mask write) is lane-contiguous: 1KB/wave-instruction.
extern "C" __global__ __launch_bounds__(256, 4)
void k_stream3(const float* __restrict__ x, const float* __restrict__ tf,
               const float* __restrict__ wsf,
               float* __restrict__ xm_out, float* __restrict__ mask_out)
{
    __shared__ float xs[RPW * HW];   // 25088 B
    __shared__ int   biL[RPW];

    const int tid = threadIdx.x;
    const float rg = 1.0f / wsf[0];
    const size_t base4 = (size_t)blockIdx.x * F4PW;   // in float4 units
    const f32x4* x4 = (const f32x4*)x + base4;
    f32x4* xs4 = (f32x4*)xs;

    // ---- pass 1: wave-contiguous loads (batched), mirror to LDS
    f32x4 u[7];
    #pragma unroll
    for (int k = 0; k < 6; ++k) u[k] = x4[tid + k * 256];
    if (tid < F4PW - 1536) u[6] = x4[tid + 1536];     // tid < 32
    #pragma unroll
    for (int k = 0; k < 6; ++k) xs4[tid + k * 256] = u[k];
    if (tid < F4PW - 1536) xs4[tid + 1536] = u[6];
    __syncthreads();

    // ---- argmax per row (8 threads per row, LDS-sourced)
    {
        const int row = tid >> 3;           // 0..31
        const int o   = tid & 7;
        float bv = -__builtin_inff(); int bi = 0;
        #pragma unroll
        for (int t = 0; t < 7; ++t) {
            const int j = o + 8 * t;        // float4 index within row
            if (j < 49) {
                f32x4 xv = xs4[row * 49 + j];
                const int k0 = j * 4;
                #pragma unroll
                for (int e = 0; e < 4; ++e) {
                    float v = xv[e];
                    if (v > bv) { bv = v; bi = k0 + e; }   // k ascends per lane
                }
            }
        }
        #pragma unroll
        for (int m = 1; m <= 4; m <<= 1) {  // reduce within each 8-lane octet
            float ov = __shfl_xor(bv, m, 64);
            int   oi = __shfl_xor(bi, m, 64);
            if (ov > bv || (ov == bv && oi < bi)) { bv = ov; bi = oi; }
        }
        if (o == 0) biL[row] = bi;
    }
    __syncthreads();

    // ---- pass 2: mask + wave-contiguous stores (x from retained u[])
    const f32x4* tf4 = (const f32x4*)tf;
    f32x4* xm4 = (f32x4*)xm_out + base4;
    f32x4* mk4 = (f32x4*)mask_out + base4;

    #pragma unroll
    for (int k = 0; k < 7; ++k) {
        const int idx = tid + k * 256;
        if (k < 6 || idx < F4PW) {
            const int rl = idx / 49;        // magic-mul const div
            const int j  = idx - rl * 49;
            const int bi = biL[rl];
            f32x4 sel = tf4[bi * 49 + j];
            f32x4 xv  = u[k];
            f32x4 mk, xm;
            #pragma unroll
            for (int e = 0; e < 4; ++e) {
                float m = fmaxf(sel[e] * rg - 0.2f, 0.0f) * 5.0f;
                mk[e] = m;
                xm[e] = xv[e] * m;
            }
            xm4[idx] = xm;
            mk4[idx] = mk;
        }
    }
}

// ---- k_gemm_loss: round-11 verbatim (known-good). Per-channel GEMM +
// softmax + MI loss. One wg (1024 thr, 16 waves) per channel. B-frags packed
// from xm fp32 (L3-hot). A-table staged to LDS fragment-contiguous ->
// conflict-free sequential ds_read_b128.
extern "C" __global__ __launch_bounds__(1024)
void k_gemm_loss(const float* __restrict__ xm, const float* __restrict__ pT,
                 const unsigned short* __restrict__ tb_bf,
                 float* __restrict__ loss_out)
{
    extern __shared__ char smem[];
    unsigned short* Alds = (unsigned short*)smem;                 // [91][512] bf16 frags
    float* s_part = (float*)(smem + ASHORTS * 2);                 // [16][208]
    float* rAs    = s_part + 16 * TROWS;                          // [208]
    float* pTs    = rAs + TROWS;                                  // [208]
    float* red    = pTs + TROWS;                                  // [16]

    const int c    = blockIdx.x;
    const int tid  = threadIdx.x;
    const int lane = tid & 63;
    const int w    = tid >> 6;
    const int l15  = lane & 15, lg = lane >> 4;

    // ---- stage A-table into LDS (5824 x 16B chunks over 1024 threads)
    {
        const f32x4* src = (const f32x4*)tb_bf;
        f32x4* dst = (f32x4*)Alds;
        #pragma unroll
        for (int it = 0; it < 6; ++it) {
            int idx = tid + it * 1024;
            if (idx < ASHORTS / 8) dst[idx] = src[idx];
        }
    }
    if (tid < TROWS) pTs[tid] = (tid < TT) ? pT[tid] : 0.0f;

    const int b = w * 16 + l15;
    const float* xrow = xm + ((size_t)b * CCH + c) * HW;

    // ---- B-frag pack straight from xm
    bf16x8 fr[7];
    #pragma unroll
    for (int kt = 0; kt < 6; ++kt) {
        f32x4 u0 = *(const f32x4*)(xrow + kt * 32 + lg * 8);
        f32x4 u1 = *(const f32x4*)(xrow + kt * 32 + lg * 8 + 4);
        #pragma unroll
        for (int e = 0; e < 4; ++e) {
            fr[kt][e]     = (short)f2bf(u0[e]);
            fr[kt][e + 4] = (short)f2bf(u1[e]);
        }
    }
    fr[6] = (bf16x8){0, 0, 0, 0, 0, 0, 0, 0};
    if (lg == 0) {
        f32x4 u0 = *(const f32x4*)(xrow + 192);
        #pragma unroll
        for (int e = 0; e < 4; ++e) fr[6][e] = (short)f2bf(u0[e]);
    }

    __syncthreads();   // A-table staged -> visible to all waves

    // ---- GEMM: tr[t = mt*16+lg*4+e][b = w*16+l15]; A-frags contiguous
    // 1024B LDS blocks: addr = (mt*7+kt)*1024B + lane*16B (seq, 0-conflict)
    f32x4 acc[13];
    #pragma unroll
    for (int mt = 0; mt < 13; ++mt) acc[mt] = (f32x4){0.f, 0.f, 0.f, 0.f};

    const unsigned short* Abase = Alds + lane * 8;
    #pragma unroll
    for (int kt = 0; kt < 7; ++kt) {
        const bf16x8 bfrag = fr[kt];
        #pragma unroll
        for (int mt = 0; mt < 13; ++mt) {
            bf16x8 afrag = *(const bf16x8*)(Abase + (mt * 7 + kt) * 512);
            acc[mt] = __builtin_amdgcn_mfma_f32_16x16x32_bf16(afrag, bfrag, acc[mt], 0, 0, 0);
        }
    }

    // ---- Phase A: exp in-register, col-sum over this wave's 16 b, cross-wave via LDS
    float* sp = s_part + w * TROWS;
    #pragma unroll
    for (int mt = 0; mt < 13; ++mt) {
        #pragma unroll
        for (int e = 0; e < 4; ++e) acc[mt][e] = __expf(acc[mt][e]);
        f32x4 s = acc[mt];
        #pragma unroll
        for (int m = 1; m <= 8; m <<= 1) {
            #pragma unroll
            for (int e = 0; e < 4; ++e) s[e] += __shfl_xor(s[e], m, 64);
        }
        if (l15 == 0) *(f32x4*)(sp + mt * 16 + lg * 4) = s;
    }
    __syncthreads();
    if (tid < TROWS) {
        float s = 0.f;
        #pragma unroll
        for (int w2 = 0; w2 < 16; ++w2) s += s_part[w2 * TROWS + tid];
        rAs[tid] = 1.0f / s;
    }
    __syncthreads();

    // ---- Phase B: p = exp*rA, px[b] = sum_t pT*p
    float px = 0.f;
    #pragma unroll
    for (int mt = 0; mt < 13; ++mt) {
        const int t0 = mt * 16 + lg * 4;
        f32x4 ra = *(const f32x4*)(rAs + t0);
        f32x4 pt = *(const f32x4*)(pTs + t0);
        #pragma unroll
        for (int e = 0; e < 4; ++e) {
            float p = acc[mt][e] * ra[e];
            acc[mt][e] = p;
            px += pt[e] * p;
        }
    }
    px += __shfl_xor(px, 16, 64);
    px += __shfl_xor(px, 32, 64);
    const float rpx = 1.0f / px;

    // ---- Phase C: loss partial = sum_t pT * p * log(p/px)
    float part = 0.f;
    #pragma unroll
    for (int mt = 0; mt < 13; ++mt) {
        const int t0 = mt * 16 + lg * 4;
        f32x4 pt = *(const f32x4*)(pTs + t0);
        #pragma unroll
        for (int e = 0; e < 4; ++e) {
            float p = acc[mt][e];
            part += pt[e] * p * __logf(p * rpx);
        }
    }
    #pragma unroll
    for (int off = 32; off >= 1; off >>= 1) part += __shfl_xor(part, off, 64);
    if (lane == 0) red[w] = part;
    __syncthreads();
    if (tid == 0) {
        float s = 0.f;
        #pragma unroll
        for (int w2 = 0; w2 < 16; ++w2) s += red[w2];
        loss_out[c] = -s;
    }
}

extern "C" void kernel_launch(void* const* d_in, const int* in_sizes, int n_in,
                              void* d_out, int out_size, void* d_ws, size_t ws_size,
                              hipStream_t stream) {
    const float* x  = (const float*)d_in[0];
    const float* tf = (const float*)d_in[1];
    const float* tb = (const float*)d_in[2];
    const float* pT = (const float*)d_in[3];

    const size_t NOUT = (size_t)BB * CCH * HW;
    float* xm_out = (float*)d_out;
    float* mk_out = xm_out + NOUT;
    float* ls_out = mk_out + NOUT;

    float* wsf = (float*)d_ws;
    unsigned short* tb_bf = (unsigned short*)((char*)d_ws + 64);   // 93184 B

    prep<<<183, 256, 0, stream>>>(tf, tb, wsf, tb_bf);
    k_stream3<<<(BB * CCH) / RPW, 256, 0, stream>>>(x, tf, wsf, xm_out, mk_out);

    const size_t SMEM = (size_t)ASHORTS * 2 + 16 * TROWS * 4
                      + TROWS * 4 + TROWS * 4 + 16 * 4;     // 108224 B
    (void)hipFuncSetAttribute((const void*)k_gemm_loss,
                              hipFuncAttributeMaxDynamicSharedMemorySize, (int)SMEM);
    k_gemm_loss<<<dim3(CCH), dim3(1024), SMEM, stream>>>(xm_out, pT, tb_bf, ls_out);
}

// Round 21
// 140.367 us; speedup vs baseline: 2.7648x; 1.0013x over previous
//
#include <hip/hip_runtime.h>

// Problem constants
#define BB 256      // batch
#define CCH 512     // channels
#define HW 196      // 14*14 spatial
#define TT 197      // templates_b rows (196 + 1 negative)
#define TROWS 208   // padded T rows (13 * 16)
#define H1FRAG (7 * 7)            // half 1: mt 0..6
#define H2FRAG (6 * 7)            // half 2: mt 7..12
#define H1SHORTS (H1FRAG * 512)   // 25088 shorts = 50176 B
#define H2SHORTS (H2FRAG * 512)   // 21504 shorts = 43008 B
#define RPW 32                    // rows per stream-wg (25KB LDS)
#define F4PW (RPW * 49)           // 1568 float4 per stream-wg

typedef __attribute__((ext_vector_type(8))) short bf16x8;
typedef __attribute__((ext_vector_type(4))) float f32x4;

__device__ __forceinline__ unsigned short f2bf(float f) {
    union { float f; unsigned u; } v; v.f = f;
    unsigned r = v.u + 0x7FFFu + ((v.u >> 16) & 1u);   // round-to-nearest-even
    return (unsigned short)(r >> 16);
}

// ---- prep: wgs 0..181 build the A-table in FRAGMENT-CONTIGUOUS order
// (mt-major): A[mt][kt][lane][j] = tb[mt*16+(lane&15)][kt*32+(lane>>4)*8+j]*tau.
// wg 182: gmax = max(templates_f) (center peak is inside every 14x14 window).
__global__ void prep(const float* __restrict__ tf, const float* __restrict__ tb,
                     float* __restrict__ wsf, unsigned short* __restrict__ tb_bf) {
    if (blockIdx.x < 182) {
        int i = blockIdx.x * 256 + threadIdx.x;     // 182*256 == 46592 exactly
        int frag = i >> 9;                          // 512 shorts per (mt,kt) block
        int s    = i & 511;
        int mt = frag / 7, kt = frag % 7;
        int lane = s >> 3, j = s & 7;
        int r = mt * 16 + (lane & 15);
        int k = kt * 32 + (lane >> 4) * 8 + j;
        const float tau = 0.5f / 196.0f;
        float v = (r < TT && k < HW) ? tb[r * HW + k] * tau : 0.0f;
        tb_bf[i] = f2bf(v);
    } else {
        __shared__ float red[256];
        float m = -1e30f;
        for (int i = threadIdx.x; i < HW * HW; i += 256) m = fmaxf(m, tf[i]);
        red[threadIdx.x] = m;
        __syncthreads();
        for (int s = 128; s > 0; s >>= 1) {
            if (threadIdx.x < s) red[threadIdx.x] = fmaxf(red[threadIdx.x], red[threadIdx.x + s]);
            __syncthreads();
        }
        if (threadIdx.x == 0) wsf[0] = red[0];
    }
}

// ---- k_stream3: WAVE-CONTIGUOUS streamer (round-20, best measured). wg = 32
// consecutive (b,c) rows. Every HBM stream is lane-contiguous (1KB/wave-instr).
extern "C" __global__ __launch_bounds__(256, 4)
void k_stream3(const float* __restrict__ x, const float* __restrict__ tf,
               const float* __restrict__ wsf,
               float* __restrict__ xm_out, float* __restrict__ mask_out)
{
    __shared__ float xs[RPW * HW];   // 25088 B
    __shared__ int   biL[RPW];

    const int tid = threadIdx.x;
    const float rg = 1.0f / wsf[0];
    const size_t base4 = (size_t)blockIdx.x * F4PW;   // in float4 units
    const f32x4* x4 = (const f32x4*)x + base4;
    f32x4* xs4 = (f32x4*)xs;

    // ---- pass 1: wave-contiguous loads (batched), mirror to LDS
    f32x4 u[7];
    #pragma unroll
    for (int k = 0; k < 6; ++k) u[k] = x4[tid + k * 256];
    if (tid < F4PW - 1536) u[6] = x4[tid + 1536];     // tid < 32
    #pragma unroll
    for (int k = 0; k < 6; ++k) xs4[tid + k * 256] = u[k];
    if (tid < F4PW - 1536) xs4[tid + 1536] = u[6];
    __syncthreads();

    // ---- argmax per row (8 threads per row, LDS-sourced)
    {
        const int row = tid >> 3;           // 0..31
        const int o   = tid & 7;
        float bv = -__builtin_inff(); int bi = 0;
        #pragma unroll
        for (int t = 0; t < 7; ++t) {
            const int j = o + 8 * t;        // float4 index within row
            if (j < 49) {
                f32x4 xv = xs4[row * 49 + j];
                const int k0 = j * 4;
                #pragma unroll
                for (int e = 0; e < 4; ++e) {
                    float v = xv[e];
                    if (v > bv) { bv = v; bi = k0 + e; }   // k ascends per lane
                }
            }
        }
        #pragma unroll
        for (int m = 1; m <= 4; m <<= 1) {  // reduce within each 8-lane octet
            float ov = __shfl_xor(bv, m, 64);
            int   oi = __shfl_xor(bi, m, 64);
            if (ov > bv || (ov == bv && oi < bi)) { bv = ov; bi = oi; }
        }
        if (o == 0) biL[row] = bi;
    }
    __syncthreads();

    // ---- pass 2: mask + wave-contiguous stores (x from retained u[])
    const f32x4* tf4 = (const f32x4*)tf;
    f32x4* xm4 = (f32x4*)xm_out + base4;
    f32x4* mk4 = (f32x4*)mask_out + base4;

    #pragma unroll
    for (int k = 0; k < 7; ++k) {
        const int idx = tid + k * 256;
        if (k < 6 || idx < F4PW) {
            const int rl = idx / 49;        // magic-mul const div
            const int j  = idx - rl * 49;
            const int bi = biL[rl];
            f32x4 sel = tf4[bi * 49 + j];
            f32x4 xv  = u[k];
            f32x4 mk, xm;
            #pragma unroll
            for (int e = 0; e < 4; ++e) {
                float m = fmaxf(sel[e] * rg - 0.2f, 0.0f) * 5.0f;
                mk[e] = m;
                xm[e] = xv[e] * m;
            }
            xm4[idx] = xm;
            mk4[idx] = mk;
        }
    }
}

// ---- k_gemm_loss: per-channel GEMM + softmax + MI loss, HALF-STAGED A-table
// (round-12 proven): 50KB buffer holds mt 0..6, restaged with mt 7..12 mid-
// GEMM. Total LDS 64KB -> 2 wgs/CU: both grid rounds co-resident, 32 waves/CU
// hiding the scattered L3-hot xm reads. Everything else round-11 verbatim.
extern "C" __global__ __launch_bounds__(1024)
void k_gemm_loss(const float* __restrict__ xm, const float* __restrict__ pT,
                 const unsigned short* __restrict__ tb_bf,
                 float* __restrict__ loss_out)
{
    extern __shared__ char smem[];
    unsigned short* Alds = (unsigned short*)smem;                 // [49][512] bf16 frags (half buffer)
    float* s_part = (float*)(smem + H1SHORTS * 2);                // [16][208]
    float* rAs    = s_part + 16 * TROWS;                          // [208]
    float* pTs    = rAs + TROWS;                                  // [208]
    float* red    = pTs + TROWS;                                  // [16]

    const int c    = blockIdx.x;
    const int tid  = threadIdx.x;
    const int lane = tid & 63;
    const int w    = tid >> 6;
    const int l15  = lane & 15, lg = lane >> 4;

    // ---- stage A-table HALF 1 (mt 0..6)
    {
        const f32x4* src = (const f32x4*)tb_bf;
        f32x4* dst = (f32x4*)Alds;
        #pragma unroll
        for (int it = 0; it < 4; ++it) {
            int idx = tid + it * 1024;
            if (idx < H1SHORTS / 8) dst[idx] = src[idx];
        }
    }
    if (tid < TROWS) pTs[tid] = (tid < TT) ? pT[tid] : 0.0f;

    const int b = w * 16 + l15;
    const float* xrow = xm + ((size_t)b * CCH + c) * HW;

    // ---- B-frag pack straight from xm
    bf16x8 fr[7];
    #pragma unroll
    for (int kt = 0; kt < 6; ++kt) {
        f32x4 u0 = *(const f32x4*)(xrow + kt * 32 + lg * 8);
        f32x4 u1 = *(const f32x4*)(xrow + kt * 32 + lg * 8 + 4);
        #pragma unroll
        for (int e = 0; e < 4; ++e) {
            fr[kt][e]     = (short)f2bf(u0[e]);
            fr[kt][e + 4] = (short)f2bf(u1[e]);
        }
    }
    fr[6] = (bf16x8){0, 0, 0, 0, 0, 0, 0, 0};
    if (lg == 0) {
        f32x4 u0 = *(const f32x4*)(xrow + 192);
        #pragma unroll
        for (int e = 0; e < 4; ++e) fr[6][e] = (short)f2bf(u0[e]);
    }

    __syncthreads();   // A half 1 staged -> visible to all waves

    // ---- GEMM pass 1: mt 0..6 (A-frags = contiguous 1024B LDS blocks)
    f32x4 acc[13];
    #pragma unroll
    for (int mt = 0; mt < 13; ++mt) acc[mt] = (f32x4){0.f, 0.f, 0.f, 0.f};

    const unsigned short* Abase = Alds + lane * 8;
    #pragma unroll
    for (int kt = 0; kt < 7; ++kt) {
        const bf16x8 bfrag = fr[kt];
        #pragma unroll
        for (int mt = 0; mt < 7; ++mt) {
            bf16x8 afrag = *(const bf16x8*)(Abase + (mt * 7 + kt) * 512);
            acc[mt] = __builtin_amdgcn_mfma_f32_16x16x32_bf16(afrag, bfrag, acc[mt], 0, 0, 0);
        }
    }

    __syncthreads();   // all waves done reading half 1

    // ---- restage A-table HALF 2 (mt 7..12)
    {
        const f32x4* src = (const f32x4*)(tb_bf + H1SHORTS);
        f32x4* dst = (f32x4*)Alds;
        #pragma unroll
        for (int it = 0; it < 3; ++it) {
            int idx = tid + it * 1024;
            if (idx < H2SHORTS / 8) dst[idx] = src[idx];
        }
    }
    __syncthreads();   // half 2 staged

    // ---- GEMM pass 2: mt 7..12
    #pragma unroll
    for (int kt = 0; kt < 7; ++kt) {
        const bf16x8 bfrag = fr[kt];
        #pragma unroll
        for (int mt = 7; mt < 13; ++mt) {
            bf16x8 afrag = *(const bf16x8*)(Abase + ((mt - 7) * 7 + kt) * 512);
            acc[mt] = __builtin_amdgcn_mfma_f32_16x16x32_bf16(afrag, bfrag, acc[mt], 0, 0, 0);
        }
    }

    // ---- Phase A: exp in-register, col-sum over this wave's 16 b, cross-wave via LDS
    float* sp = s_part + w * TROWS;
    #pragma unroll
    for (int mt = 0; mt < 13; ++mt) {
        #pragma unroll
        for (int e = 0; e < 4; ++e) acc[mt][e] = __expf(acc[mt][e]);
        f32x4 s = acc[mt];
        #pragma unroll
        for (int m = 1; m <= 8; m <<= 1) {
            #pragma unroll
            for (int e = 0; e < 4; ++e) s[e] += __shfl_xor(s[e], m, 64);
        }
        if (l15 == 0) *(f32x4*)(sp + mt * 16 + lg * 4) = s;
    }
    __syncthreads();
    if (tid < TROWS) {
        float s = 0.f;
        #pragma unroll
        for (int w2 = 0; w2 < 16; ++w2) s += s_part[w2 * TROWS + tid];
        rAs[tid] = 1.0f / s;
    }
    __syncthreads();

    // ---- Phase B: p = exp*rA, px[b] = sum_t pT*p
    float px = 0.f;
    #pragma unroll
    for (int mt = 0; mt < 13; ++mt) {
        const int t0 = mt * 16 + lg * 4;
        f32x4 ra = *(const f32x4*)(rAs + t0);
        f32x4 pt = *(const f32x4*)(pTs + t0);
        #pragma unroll
        for (int e = 0; e < 4; ++e) {
            float p = acc[mt][e] * ra[e];
            acc[mt][e] = p;
            px += pt[e] * p;
        }
    }
    px += __shfl_xor(px, 16, 64);
    px += __shfl_xor(px, 32, 64);
    const float rpx = 1.0f / px;

    // ---- Phase C: loss partial = sum_t pT * p * log(p/px)
    float part = 0.f;
    #pragma unroll
    for (int mt = 0; mt < 13; ++mt) {
        const int t0 = mt * 16 + lg * 4;
        f32x4 pt = *(const f32x4*)(pTs + t0);
        #pragma unroll
        for (int e = 0; e < 4; ++e) {
            float p = acc[mt][e];
            part += pt[e] * p * __logf(p * rpx);
        }
    }
    #pragma unroll
    for (int off = 32; off >= 1; off >>= 1) part += __shfl_xor(part, off, 64);
    if (lane == 0) red[w] = part;
    __syncthreads();
    if (tid == 0) {
        float s = 0.f;
        #pragma unroll
        for (int w2 = 0; w2 < 16; ++w2) s += red[w2];
        loss_out[c] = -s;
    }
}

extern "C" void kernel_launch(void* const* d_in, const int* in_sizes, int n_in,
                              void* d_out, int out_size, void* d_ws, size_t ws_size,
                              hipStream_t stream) {
    const float* x  = (const float*)d_in[0];
    const float* tf = (const float*)d_in[1];
    const float* tb = (const float*)d_in[2];
    const float* pT = (const float*)d_in[3];

    const size_t NOUT = (size_t)BB * CCH * HW;
    float* xm_out = (float*)d_out;
    float* mk_out = xm_out + NOUT;
    float* ls_out = mk_out + NOUT;

    float* wsf = (float*)d_ws;
    unsigned short* tb_bf = (unsigned short*)((char*)d_ws + 64);   // 93184 B

    prep<<<183, 256, 0, stream>>>(tf, tb, wsf, tb_bf);
    k_stream3<<<(BB * CCH) / RPW, 256, 0, stream>>>(x, tf, wsf, xm_out, mk_out);

    const size_t SMEM = (size_t)H1SHORTS * 2             // A half buffer: 50176
                      + 16 * TROWS * 4                   // s_part: 13312
                      + TROWS * 4 + TROWS * 4 + 16 * 4;  // rAs + pTs + red = 65344
    (void)hipFuncSetAttribute((const void*)k_gemm_loss,
                              hipFuncAttributeMaxDynamicSharedMemorySize, (int)SMEM);
    k_gemm_loss<<<dim3(CCH), dim3(1024), SMEM, stream>>>(xm_out, pT, tb_bf, ls_out);
}